// Round 15
// baseline (150.230 us; speedup 1.0000x reference)
//
#include <hip/hip_runtime.h>
#include <hip/hip_bf16.h>

// B=4, S=4096, D=2048, H=16, dh=128, R=4, WIN=128, Cs=1024, ws=3968.
// Chunks 992..1023 live; chunks <=991 collapse to v[:,0,:].
//
// Structure (5 dispatches) — A-DIRECT GEMM (B-only LDS staging):
//   prep_kernel  : weights f32->bf16 (Wb), window -> bf16 (Awx), means -> bf16 (Aq)
//   qkv_kernel   : 128x128/BK64 GEMM; A-fragments read DIRECT from L2-resident
//                  Aq/Awx (no LDS); B via global_load_lds + XOR swizzle, 32 KB
//                  dbuf. splitK=4, 576 blocks, XCD-chunked task decode
//                  (each XCD: nt-pair x all gy -> B panels L2-local).
//   attn_kernel  : sums 4 partial slices during staging, 32x128 masked softmax
//   o_kernel     : same body, splitK=2 -> 2 f32 Yo slices
//   resize_kernel: sums 2 Yo slices, clamped lerp upsample -> d_out

typedef __attribute__((ext_vector_type(8))) short short8;
typedef __attribute__((ext_vector_type(4))) float f32x4;

#define QP_SLICE  (128 * 2048)    // shorts per Q partial slice
#define KV_SLICE  (512 * 2048)    // shorts per K/V partial slice
#define YO_STRIDE (132 * 2048)    // floats per Yo partial slice

__device__ __forceinline__ unsigned short f2bf(float f){
  unsigned int x = __float_as_uint(f);
  return (unsigned short)((x + 0x7fffu + ((x >> 16) & 1u)) >> 16);
}
__device__ __forceinline__ float bf2f(unsigned short u){
  return __uint_as_float(((unsigned int)u) << 16);
}
__device__ __forceinline__ float bflo(unsigned int u){ return __uint_as_float(u << 16); }
__device__ __forceinline__ float bfhi(unsigned int u){ return __uint_as_float(u & 0xffff0000u); }
__device__ __forceinline__ unsigned int pk2(float lo, float hi){
  return ((unsigned int)f2bf(hi) << 16) | (unsigned int)f2bf(lo);
}
__device__ __forceinline__ short8 cvt8(float4 x, float4 y){
  union { unsigned int u[4]; short8 s; } r;
  r.u[0] = pk2(x.x, x.y); r.u[1] = pk2(x.z, x.w);
  r.u[2] = pk2(y.x, y.y); r.u[3] = pk2(y.z, y.w);
  return r.s;
}

// ---------- prep: weights + window + chunk-means -> bf16 ----------
__global__ __launch_bounds__(256) void prep_kernel(
    const float* __restrict__ inp,
    const float* __restrict__ Wq, const float* __restrict__ Wk,
    const float* __restrict__ Wv, const float* __restrict__ Wo,
    unsigned short* __restrict__ Wb,
    unsigned short* __restrict__ Awx, unsigned short* __restrict__ Aq)
{
  const int bx = blockIdx.x;
  if (bx < 8192){
    const int idx = bx * 256 + threadIdx.x;
    const int w = idx >> 19;
    const int sub = idx & 524287;
    const float* src = (w == 0) ? Wq : (w == 1) ? Wk : (w == 2) ? Wv : Wo;
    const float* p = src + (size_t)sub * 8;
    *(short8*)&Wb[(size_t)w * 4194304 + (size_t)sub * 8] =
        cvt8(*(const float4*)p, *(const float4*)(p + 4));
  } else if (bx < 8704){
    const int idx = (bx - 8192) * 256 + threadIdx.x;
    const int b = idx >> 15;
    const int j = (idx >> 8) & 127;
    const int d8 = (idx & 255) * 8;
    const float* p = inp + ((size_t)b * 4096 + 3968 + j) * 2048 + d8;
    *(short8*)&Awx[((size_t)b * 128 + j) * 2048 + d8] =
        cvt8(*(const float4*)p, *(const float4*)(p + 4));
  } else {
    const int idx = (bx - 8704) * 256 + threadIdx.x;
    const int b = idx >> 13;
    const int c = (idx >> 8) & 31;
    const int d8 = (idx & 255) * 8;
    const float* p = inp + ((size_t)b * 4096 + 3968 + 4 * c) * 2048 + d8;
    float4 x0 = *(const float4*)(p);
    float4 x1 = *(const float4*)(p + 2048);
    float4 x2 = *(const float4*)(p + 4096);
    float4 x3 = *(const float4*)(p + 6144);
    float4 y0 = *(const float4*)(p + 4);
    float4 y1 = *(const float4*)(p + 2052);
    float4 y2 = *(const float4*)(p + 4100);
    float4 y3 = *(const float4*)(p + 6148);
    float4 xm, ym;
    xm.x = 0.25f * (x0.x + x1.x + x2.x + x3.x);
    xm.y = 0.25f * (x0.y + x1.y + x2.y + x3.y);
    xm.z = 0.25f * (x0.z + x1.z + x2.z + x3.z);
    xm.w = 0.25f * (x0.w + x1.w + x2.w + x3.w);
    ym.x = 0.25f * (y0.x + y1.x + y2.x + y3.x);
    ym.y = 0.25f * (y0.y + y1.y + y2.y + y3.y);
    ym.z = 0.25f * (y0.z + y1.z + y2.z + y3.z);
    ym.w = 0.25f * (y0.w + y1.w + y2.w + y3.w);
    *(short8*)&Aq[((size_t)b * 32 + c) * 2048 + d8] = cvt8(xm, ym);
  }
}

// ---- stage one 128x64 B-tile into LDS via global_load_lds.
// Linear LDS dest; global source column pre-swizzled (unit ^ (row&7)); reads
// apply the same XOR -> conflict-free (rule 21).
__device__ __forceinline__ void stage_b(
    const unsigned short* __restrict__ W, int n0, int kt,
    unsigned short* Bs, int wid, int lane)
{
  const int r  = lane >> 3;
  const int ug = ((lane & 7) ^ r) * 8;
  #pragma unroll
  for (int i = 0; i < 4; ++i){
    const int c = wid * 4 + i;
    __builtin_amdgcn_global_load_lds(
        (const __attribute__((address_space(1))) void*)(W + (size_t)(n0 + c * 8 + r) * 2048 + kt + ug),
        (__attribute__((address_space(3))) void*)(Bs + c * 512),
        16, 0, 0);
  }
}

// ---- GEMM slice: C[row0..+127, n0..+127] = A[.,kbase..+64*nsteps) @ W^T.
// A-fragments DIRECT from global (L2-resident Aq/Awx/Ao); B via gload_lds
// double buffer (32 KB). 4 waves (2x2 of 64x64), 16x16x32 bf16 MFMA.
template<bool OUT_BF16>
__device__ __forceinline__ void gemm_body(
    const unsigned short* __restrict__ A, const unsigned short* __restrict__ W,
    unsigned short* __restrict__ Cb, float* __restrict__ Cf,
    int M, int row0, int n0, int kbase, int nsteps,
    unsigned short* L)    // 2 x 8192 shorts (B dbuf)
{
  const int tid  = threadIdx.x;
  const int lane = tid & 63;
  const int wid  = tid >> 6;
  const int wr = wid >> 1, wc = wid & 1;

  // per-thread A row pointers (fixed rows; only k advances)
  const unsigned short* Ar[4];
  #pragma unroll
  for (int f = 0; f < 4; ++f){
    int ar = row0 + wr * 64 + f * 16 + (lane & 15);
    if (ar > M - 1) ar = M - 1;
    Ar[f] = A + (size_t)ar * 2048 + (lane >> 4) * 8;
  }

  f32x4 acc[4][4] = {};

  stage_b(W, n0, kbase, L, wid, lane);
  int cur = 0;

  for (int t = 0; t < nsteps; ++t){
    __syncthreads();   // drains gload -> B buf[cur] ready; prev reads done
    if (t + 1 < nsteps)
      stage_b(W, n0, kbase + (t + 1) * 64, L + (cur ^ 1) * 8192, wid, lane);
    const unsigned short* Bs = L + cur * 8192;
    const int kt = kbase + t * 64;
    #pragma unroll
    for (int ks = 0; ks < 2; ++ks){
      short8 av[4], bv[4];
      const int unit = ks * 4 + (lane >> 4);
      #pragma unroll
      for (int f = 0; f < 4; ++f)
        av[f] = *(const short8*)(Ar[f] + kt + ks * 32);
      #pragma unroll
      for (int n = 0; n < 4; ++n){
        const int row = wc * 64 + n * 16 + (lane & 15);
        bv[n] = *(const short8*)&Bs[row * 64 + ((unit ^ (row & 7)) * 8)];
      }
      #pragma unroll
      for (int f = 0; f < 4; ++f)
        #pragma unroll
        for (int n = 0; n < 4; ++n)
          acc[f][n] = __builtin_amdgcn_mfma_f32_16x16x32_bf16(av[f], bv[n], acc[f][n], 0, 0, 0);
    }
    cur ^= 1;
  }

  #pragma unroll
  for (int f = 0; f < 4; ++f){
    #pragma unroll
    for (int n = 0; n < 4; ++n){
      const int col = n0 + wc * 64 + n * 16 + (lane & 15);
      #pragma unroll
      for (int r = 0; r < 4; ++r){
        const int row = row0 + wr * 64 + f * 16 + (lane >> 4) * 4 + r;
        if (row < M){
          if (OUT_BF16) Cb[(size_t)row * 2048 + col] = f2bf(acc[f][n][r]);
          else          Cf[(size_t)row * 2048 + col] = acc[f][n][r];
        }
      }
    }
  }
}

// qkv: 576 blocks, splitK=4 (K-slices of 512, 8 steps). XCD-chunked decode:
// xcd = flat&7 (HW round-robin heuristic), w = flat>>3 in [0,72):
//   nt = xcd*2 + (w>=36); g = w%36:
//   g<4 -> Q ksp=g; g<20 -> K idx=g-4 (mt=idx>>2, ksp=idx&3); else V.
// Each XCD touches only its nt-pair's B panels (~3 MB -> private-L2-local).
__global__ __launch_bounds__(256, 3) void qkv_kernel(
    const unsigned short* __restrict__ Aq, const unsigned short* __restrict__ Awx,
    const unsigned short* __restrict__ Wb,
    unsigned short* __restrict__ Qp, unsigned short* __restrict__ Kp,
    unsigned short* __restrict__ Vp)
{
  __shared__ __align__(16) unsigned short L[16384];   // 32 KB (B dbuf)
  const int flat = blockIdx.x;
  const int xcd = flat & 7;
  const int w   = flat >> 3;
  const int nt  = (xcd << 1) | (w >= 36 ? 1 : 0);
  const int g   = (w >= 36) ? w - 36 : w;
  if (g < 4){
    gemm_body<true>(Aq, Wb, Qp + g * QP_SLICE, nullptr,
                    128, 0, nt * 128, g * 512, 8, L);
  } else if (g < 20){
    const int idx = g - 4, mt = idx >> 2, ksp = idx & 3;
    gemm_body<true>(Awx, Wb + 4194304, Kp + ksp * KV_SLICE, nullptr,
                    512, mt * 128, nt * 128, ksp * 512, 8, L);
  } else {
    const int idx = g - 20, mt = idx >> 2, ksp = idx & 3;
    gemm_body<true>(Awx, Wb + 8388608, Vp + ksp * KV_SLICE, nullptr,
                    512, mt * 128, nt * 128, ksp * 512, 8, L);
  }
}

// O-projection: splitK=2, grid (16 nt, 2 mt, 2 ksp) -> 2 f32 Yo slices, 16 steps.
__global__ __launch_bounds__(256, 3) void o_kernel(
    const unsigned short* __restrict__ Ao, const unsigned short* __restrict__ Wb,
    float* __restrict__ Yop)
{
  __shared__ __align__(16) unsigned short L[16384];
  gemm_body<false>(Ao, Wb + 12582912, nullptr, Yop + (size_t)blockIdx.z * YO_STRIDE,
                   132, blockIdx.y * 128, blockIdx.x * 128, blockIdx.z * 1024, 16, L);
}

// ---------------- attention: chunks 992..1023 only, per (b,h) block ----------------
// Sums the 4 bf16 split-K partial slices of Q/K/V during LDS staging.
__global__ __launch_bounds__(256) void attn_kernel(
    const unsigned short* __restrict__ Qp, const unsigned short* __restrict__ Kp,
    const unsigned short* __restrict__ Vp, const int* __restrict__ amask,
    unsigned short* __restrict__ Ao)
{
  const int b = blockIdx.x >> 4;
  const int h = blockIdx.x & 15;
  __shared__ float Qs[32][129];
  __shared__ unsigned int Ks[128][65];
  __shared__ unsigned int Vs[128][65];
  __shared__ float Wt[32][132];
  __shared__ float msk[128];
  const int tid = threadIdx.x;

  for (int i = tid; i < 32 * 128; i += 256){
    int cq = i >> 7, d = i & 127;
    size_t off = (size_t)(b * 32 + cq) * 2048 + h * 128 + d;
    Qs[cq][d] = bf2f(Qp[off]) + bf2f(Qp[off + QP_SLICE]) +
                bf2f(Qp[off + 2 * QP_SLICE]) + bf2f(Qp[off + 3 * QP_SLICE]);
  }
  for (int i = tid; i < 128 * 64; i += 256){
    int j = i >> 6, du = i & 63;
    size_t off = (size_t)(b * 128 + j) * 2048 + h * 128 + du * 2;
    unsigned int k0 = *(const unsigned int*)(Kp + off);
    unsigned int k1 = *(const unsigned int*)(Kp + off + KV_SLICE);
    unsigned int k2 = *(const unsigned int*)(Kp + off + 2 * KV_SLICE);
    unsigned int k3 = *(const unsigned int*)(Kp + off + 3 * KV_SLICE);
    unsigned int v0 = *(const unsigned int*)(Vp + off);
    unsigned int v1 = *(const unsigned int*)(Vp + off + KV_SLICE);
    unsigned int v2 = *(const unsigned int*)(Vp + off + 2 * KV_SLICE);
    unsigned int v3 = *(const unsigned int*)(Vp + off + 3 * KV_SLICE);
    Ks[j][du] = pk2(bflo(k0) + bflo(k1) + bflo(k2) + bflo(k3),
                    bfhi(k0) + bfhi(k1) + bfhi(k2) + bfhi(k3));
    Vs[j][du] = pk2(bflo(v0) + bflo(v1) + bflo(v2) + bflo(v3),
                    bfhi(v0) + bfhi(v1) + bfhi(v2) + bfhi(v3));
  }
  if (tid < 128){
    msk[tid] = (amask[b * 4096 + 3968 + tid] != 0) ? 1.f : 0.f;
    size_t off = (size_t)(b * 128) * 2048 + h * 128 + tid;
    Ao[(size_t)(b * 33) * 2048 + h * 128 + tid] =
        f2bf(bf2f(Vp[off]) + bf2f(Vp[off + KV_SLICE]) +
             bf2f(Vp[off + 2 * KV_SLICE]) + bf2f(Vp[off + 3 * KV_SLICE]));
  }
  __syncthreads();

  const int cq = tid >> 3, jg = tid & 7;
  const int jmax = 4 * cq + 3;   // causal: j <= 4*cq+3 for chunk 992+cq
  const float scale = 0.088388347648318447f; // 1/sqrt(128)

  float s[16];
  {
    float sacc[16];
    #pragma unroll
    for (int jj = 0; jj < 16; ++jj) sacc[jj] = 0.f;
    for (int du = 0; du < 64; ++du){
      float q0 = Qs[cq][2 * du], q1 = Qs[cq][2 * du + 1];
      #pragma unroll
      for (int jj = 0; jj < 16; ++jj){
        unsigned int u = Ks[jg * 16 + jj][du];
        sacc[jj] += q0 * bflo(u) + q1 * bfhi(u);
      }
    }
    #pragma unroll
    for (int jj = 0; jj < 16; ++jj){
      int j = jg * 16 + jj;
      bool ok = (j <= jmax) && (msk[j] > 0.5f);
      s[jj] = ok ? sacc[jj] * scale : -1e9f;
    }
  }
  float m = s[0];
  #pragma unroll
  for (int jj = 1; jj < 16; ++jj) m = fmaxf(m, s[jj]);
  #pragma unroll
  for (int off = 1; off < 8; off <<= 1) m = fmaxf(m, __shfl_xor(m, off, 8));
  float sum = 0.f;
  #pragma unroll
  for (int jj = 0; jj < 16; ++jj){ s[jj] = expf(s[jj] - m); sum += s[jj]; }
  #pragma unroll
  for (int off = 1; off < 8; off <<= 1) sum += __shfl_xor(sum, off, 8);
  const float inv = 1.f / sum;
  #pragma unroll
  for (int jj = 0; jj < 16; ++jj) Wt[cq][jg * 16 + jj] = s[jj] * inv;
  __syncthreads();

  const int dg = tid & 7;
  float o[16];
  #pragma unroll
  for (int e = 0; e < 16; ++e) o[e] = 0.f;
  for (int j = 0; j < 128; ++j){
    float w = Wt[cq][j];
    #pragma unroll
    for (int du = 0; du < 8; ++du){
      unsigned int u = Vs[j][dg * 8 + du];
      o[2 * du]     += w * bflo(u);
      o[2 * du + 1] += w * bfhi(u);
    }
  }
  unsigned short* dst = Ao + (size_t)(b * 33 + 1 + cq) * 2048 + h * 128 + dg * 16;
  #pragma unroll
  for (int e = 0; e < 16; ++e) dst[e] = f2bf(o[e]);
}

// -------- resize: sum 2 Yo slices, linear upsample Cs=1024 -> S=4096 --------
__global__ __launch_bounds__(256) void resize_kernel(
    const float* __restrict__ Yop, float* __restrict__ out)
{
  const int rowid = blockIdx.x;
  const int b = rowid >> 12;
  const int i = rowid & 4095;
  float c  = i * 0.25f - 0.375f;
  float fl = floorf(c);
  int   j0 = (int)fl;
  float f  = c - fl;
  int   j1 = j0 + 1;
  j0 = max(0, min(j0, 1023));
  j1 = max(0, min(j1, 1023));
  const int ri0 = b * 33 + (j0 <= 991 ? 0 : j0 - 991);
  const int ri1 = b * 33 + (j1 <= 991 ? 0 : j1 - 991);
  const float* r0 = Yop + (size_t)ri0 * 2048;
  const float* r1 = Yop + (size_t)ri1 * 2048;
  float* op = out + (size_t)rowid * 2048;
  const int t = threadIdx.x;
  const bool same = (ri0 == ri1);
  #pragma unroll
  for (int q = 0; q < 2; ++q){
    int d = q * 1024 + t * 4;
    float4 a0 = *(const float4*)(r0 + d);
    float4 a1 = *(const float4*)(r0 + d + YO_STRIDE);
    float4 a;
    a.x = a0.x + a1.x; a.y = a0.y + a1.y; a.z = a0.z + a1.z; a.w = a0.w + a1.w;
    float4 o = a;
    if (!same){
      float4 b0 = *(const float4*)(r1 + d);
      float4 b1 = *(const float4*)(r1 + d + YO_STRIDE);
      float4 bb;
      bb.x = b0.x + b1.x; bb.y = b0.y + b1.y; bb.z = b0.z + b1.z; bb.w = b0.w + b1.w;
      o.x = a.x + f * (bb.x - a.x);
      o.y = a.y + f * (bb.y - a.y);
      o.z = a.z + f * (bb.z - a.z);
      o.w = a.w + f * (bb.w - a.w);
    }
    *(float4*)(op + d) = o;
  }
}

extern "C" void kernel_launch(void* const* d_in, const int* in_sizes, int n_in,
                              void* d_out, int out_size, void* d_ws, size_t ws_size,
                              hipStream_t stream)
{
  const float* inp   = (const float*)d_in[0];
  const int*   amask = (const int*)d_in[1];
  const float* Wq = (const float*)d_in[2];
  const float* Wk = (const float*)d_in[3];
  const float* Wv = (const float*)d_in[4];
  const float* Wo = (const float*)d_in[5];
  float* out = (float*)d_out;

  char* ws = (char*)d_ws;
  unsigned short* Wb  = (unsigned short*)(ws);             // 4 x 2048x2048 bf16 (33.5 MB)
  unsigned short* Aq  = (unsigned short*)(ws + 33554432);  // 128 x 2048 bf16
  unsigned short* Awx = (unsigned short*)(ws + 34078720);  // 512 x 2048 bf16
  unsigned short* Qp  = (unsigned short*)(ws + 36175872);  // 4 x [128x2048] bf16 partials
  unsigned short* Kp  = (unsigned short*)(ws + 38273024);  // 4 x [512x2048] bf16 partials
  unsigned short* Vp  = (unsigned short*)(ws + 46661632);  // 4 x [512x2048] bf16 partials
  unsigned short* Ao  = (unsigned short*)(ws + 55050240);  // 132 x 2048 bf16 (1 MB region)
  float*          Yop = (float*)(ws + 56098816);           // 2 x [132x2048] f32 partials

  prep_kernel<<<8832, 256, 0, stream>>>(inp, Wq, Wk, Wv, Wo, Wb, Awx, Aq);
  qkv_kernel<<<576, 256, 0, stream>>>(Aq, Awx, Wb, Qp, Kp, Vp);
  attn_kernel<<<64, 256, 0, stream>>>(Qp, Kp, Vp, amask, Ao);
  o_kernel<<<dim3(16, 2, 2), 256, 0, stream>>>(Ao, Wb, Yop);
  resize_kernel<<<16384, 256, 0, stream>>>(Yop, out);
}

// Round 16
// 116.108 us; speedup vs baseline: 1.2939x; 1.2939x over previous
//
#include <hip/hip_runtime.h>
#include <hip/hip_bf16.h>

// B=4, S=4096, D=2048, H=16, dh=128, R=4, WIN=128, Cs=1024, ws=3968.
// Chunks 992..1023 live; chunks <=991 collapse to v[:,0,:].
//
// Structure (5 dispatches) — r14 skeleton + counted-vmcnt deep pipeline GEMM:
//   prep_kernel  : weights f32->bf16 (Wb), window -> bf16 (Awx), means -> bf16 (Aq)
//   qkv_kernel   : 128x128 GEMM, BK=32, 4-buffer LDS (64 KB), global_load_lds
//                  issued 2 tiles ahead, s_waitcnt vmcnt(8) + raw s_barrier
//                  (never drain to 0 in-loop). splitK=2, XCD-chunked remap.
//   attn_kernel  : sums 2 partial slices during staging, 32x128 masked softmax
//   o_kernel     : same GEMM body, splitK=2 -> 2 f32 Yo slices
//   resize_kernel: sums 2 Yo slices, clamped lerp upsample -> d_out

typedef __attribute__((ext_vector_type(8))) short short8;
typedef __attribute__((ext_vector_type(4))) float f32x4;

#define QP_SLICE  (128 * 2048)    // shorts per Q partial slice
#define KV_SLICE  (512 * 2048)    // shorts per K/V partial slice
#define YO_STRIDE (132 * 2048)    // floats per Yo partial slice

__device__ __forceinline__ unsigned short f2bf(float f){
  unsigned int x = __float_as_uint(f);
  return (unsigned short)((x + 0x7fffu + ((x >> 16) & 1u)) >> 16);
}
__device__ __forceinline__ float bf2f(unsigned short u){
  return __uint_as_float(((unsigned int)u) << 16);
}
__device__ __forceinline__ float bflo(unsigned int u){ return __uint_as_float(u << 16); }
__device__ __forceinline__ float bfhi(unsigned int u){ return __uint_as_float(u & 0xffff0000u); }
__device__ __forceinline__ unsigned int pk2(float lo, float hi){
  return ((unsigned int)f2bf(hi) << 16) | (unsigned int)f2bf(lo);
}
__device__ __forceinline__ short8 cvt8(float4 x, float4 y){
  union { unsigned int u[4]; short8 s; } r;
  r.u[0] = pk2(x.x, x.y); r.u[1] = pk2(x.z, x.w);
  r.u[2] = pk2(y.x, y.y); r.u[3] = pk2(y.z, y.w);
  return r.s;
}

// ---------- prep: weights + window + chunk-means -> bf16 ----------
__global__ __launch_bounds__(256) void prep_kernel(
    const float* __restrict__ inp,
    const float* __restrict__ Wq, const float* __restrict__ Wk,
    const float* __restrict__ Wv, const float* __restrict__ Wo,
    unsigned short* __restrict__ Wb,
    unsigned short* __restrict__ Awx, unsigned short* __restrict__ Aq)
{
  const int bx = blockIdx.x;
  if (bx < 8192){
    const int idx = bx * 256 + threadIdx.x;
    const int w = idx >> 19;
    const int sub = idx & 524287;
    const float* src = (w == 0) ? Wq : (w == 1) ? Wk : (w == 2) ? Wv : Wo;
    const float* p = src + (size_t)sub * 8;
    *(short8*)&Wb[(size_t)w * 4194304 + (size_t)sub * 8] =
        cvt8(*(const float4*)p, *(const float4*)(p + 4));
  } else if (bx < 8704){
    const int idx = (bx - 8192) * 256 + threadIdx.x;
    const int b = idx >> 15;
    const int j = (idx >> 8) & 127;
    const int d8 = (idx & 255) * 8;
    const float* p = inp + ((size_t)b * 4096 + 3968 + j) * 2048 + d8;
    *(short8*)&Awx[((size_t)b * 128 + j) * 2048 + d8] =
        cvt8(*(const float4*)p, *(const float4*)(p + 4));
  } else {
    const int idx = (bx - 8704) * 256 + threadIdx.x;
    const int b = idx >> 13;
    const int c = (idx >> 8) & 31;
    const int d8 = (idx & 255) * 8;
    const float* p = inp + ((size_t)b * 4096 + 3968 + 4 * c) * 2048 + d8;
    float4 x0 = *(const float4*)(p);
    float4 x1 = *(const float4*)(p + 2048);
    float4 x2 = *(const float4*)(p + 4096);
    float4 x3 = *(const float4*)(p + 6144);
    float4 y0 = *(const float4*)(p + 4);
    float4 y1 = *(const float4*)(p + 2052);
    float4 y2 = *(const float4*)(p + 4100);
    float4 y3 = *(const float4*)(p + 6148);
    float4 xm, ym;
    xm.x = 0.25f * (x0.x + x1.x + x2.x + x3.x);
    xm.y = 0.25f * (x0.y + x1.y + x2.y + x3.y);
    xm.z = 0.25f * (x0.z + x1.z + x2.z + x3.z);
    xm.w = 0.25f * (x0.w + x1.w + x2.w + x3.w);
    ym.x = 0.25f * (y0.x + y1.x + y2.x + y3.x);
    ym.y = 0.25f * (y0.y + y1.y + y2.y + y3.y);
    ym.z = 0.25f * (y0.z + y1.z + y2.z + y3.z);
    ym.w = 0.25f * (y0.w + y1.w + y2.w + y3.w);
    *(short8*)&Aq[((size_t)b * 32 + c) * 2048 + d8] = cvt8(xm, ym);
  }
}

// ---- stage one 128x32 A-tile + 128x32 B-tile into one 16 KB LDS buffer via
// global_load_lds. Linear LDS [128][32]; global source 16B-unit pre-swizzled
// by (unit ^ (row&3)) so the swizzled ds_read is 2-way-bank (free). Each wave
// stages rows wid*32..wid*32+31 (2 instructions of 16 rows each per operand).
__device__ __forceinline__ void stage32(
    const unsigned short* __restrict__ A, const unsigned short* __restrict__ W,
    int row0, int n0, int kt,
    unsigned short* buf, int wid, int lane)
{
  #pragma unroll
  for (int i = 0; i < 2; ++i){
    const int rbase = (wid << 5) + i * 16;       // first row of this instruction
    const int r = rbase + (lane >> 2);
    const int ug = ((lane & 3) ^ (r & 3)) * 8;   // swizzled global 16B-unit
    __builtin_amdgcn_global_load_lds(
        (const __attribute__((address_space(1))) void*)(A + (size_t)(row0 + r) * 2048 + kt + ug),
        (__attribute__((address_space(3))) void*)(buf + rbase * 32),
        16, 0, 0);
    __builtin_amdgcn_global_load_lds(
        (const __attribute__((address_space(1))) void*)(W + (size_t)(n0 + r) * 2048 + kt + ug),
        (__attribute__((address_space(3))) void*)(buf + 4096 + rbase * 32),
        16, 0, 0);
  }
}

// ---- GEMM slice: C[row0..+127, n0..+127] = A[.,kbase..+32*nsteps) @ W^T.
// BK=32, 4 LDS buffers (16 KB each), loads 2 tiles ahead, counted vmcnt.
// 4 waves (2x2 of 64x64), 16x16x32 bf16 MFMA, 16 MFMA/step.
template<bool OUT_BF16>
__device__ __forceinline__ void gemm_body(
    const unsigned short* __restrict__ A, const unsigned short* __restrict__ W,
    unsigned short* __restrict__ Cb, float* __restrict__ Cf,
    int M, int row0, int n0, int kbase, int nsteps,
    unsigned short* L)    // 4 x 8192 shorts = 64 KB
{
  const int tid  = threadIdx.x;
  const int lane = tid & 63;
  const int wid  = tid >> 6;
  const int wr = wid >> 1, wc = wid & 1;

  f32x4 acc[4][4] = {};

  // prologue: stage tiles 0 and 1 (4 gload instructions each)
  stage32(A, W, row0, n0, kbase,      L,        wid, lane);
  stage32(A, W, row0, n0, kbase + 32, L + 8192, wid, lane);

  for (int t = 0; t < nsteps; ++t){
    if (t + 2 < nsteps)
      stage32(A, W, row0, n0, kbase + (t + 2) * 32, L + ((t + 2) & 3) * 8192, wid, lane);
    // retire the OLDEST 4 loads (tile t); keep tiles t+1/t+2 in flight.
    if (t + 2 < nsteps)      asm volatile("s_waitcnt vmcnt(8)" ::: "memory");
    else if (t + 1 < nsteps) asm volatile("s_waitcnt vmcnt(4)" ::: "memory");
    else                     asm volatile("s_waitcnt vmcnt(0)" ::: "memory");
    __builtin_amdgcn_s_barrier();
    __builtin_amdgcn_sched_barrier(0);

    const unsigned short* As = L + (t & 3) * 8192;
    const unsigned short* Bs = As + 4096;
    const int u = lane >> 4;                     // k-octet 0..3
    short8 av[4], bv[4];
    #pragma unroll
    for (int f = 0; f < 4; ++f){
      const int row = wr * 64 + f * 16 + (lane & 15);
      av[f] = *(const short8*)&As[row * 32 + ((u ^ (row & 3)) * 8)];
    }
    #pragma unroll
    for (int n = 0; n < 4; ++n){
      const int row = wc * 64 + n * 16 + (lane & 15);
      bv[n] = *(const short8*)&Bs[row * 32 + ((u ^ (row & 3)) * 8)];
    }
    #pragma unroll
    for (int f = 0; f < 4; ++f)
      #pragma unroll
      for (int n = 0; n < 4; ++n)
        acc[f][n] = __builtin_amdgcn_mfma_f32_16x16x32_bf16(av[f], bv[n], acc[f][n], 0, 0, 0);
  }

  // epilogue: C/D layout col=lane&15, row=(lane>>4)*4+reg
  #pragma unroll
  for (int f = 0; f < 4; ++f){
    #pragma unroll
    for (int n = 0; n < 4; ++n){
      const int col = n0 + wc * 64 + n * 16 + (lane & 15);
      #pragma unroll
      for (int r = 0; r < 4; ++r){
        const int row = row0 + wr * 64 + f * 16 + (lane >> 4) * 4 + r;
        if (row < M){
          if (OUT_BF16) Cb[(size_t)row * 2048 + col] = f2bf(acc[f][n][r]);
          else          Cf[(size_t)row * 2048 + col] = acc[f][n][r];
        }
      }
    }
  }
}

// 288 blocks; bijective XCD-chunked remap (288 = 8 XCDs x 36).
// fid -> nt = fid&15, gy = fid>>4:
//   gy<2 -> Q (ksp=gy); [2,10) -> K; [10,18) -> V (idx: mt=idx>>1, ksp=idx&1)
// splitK=2, K-slice=1024, 32 BK=32 steps.
__global__ __launch_bounds__(256, 2) void qkv_kernel(
    const unsigned short* __restrict__ Aq, const unsigned short* __restrict__ Awx,
    const unsigned short* __restrict__ Wb,
    unsigned short* __restrict__ Qp, unsigned short* __restrict__ Kp,
    unsigned short* __restrict__ Vp)
{
  __shared__ __align__(16) unsigned short L[32768];   // 4 x 16 KB
  const int flat = blockIdx.x + (blockIdx.y << 4);
  const int fid  = (flat & 7) * 36 + (flat >> 3);
  const int nt = fid & 15, gy = fid >> 4;
  if (gy < 2){
    gemm_body<true>(Aq, Wb, Qp + gy * QP_SLICE, nullptr,
                    128, 0, nt * 128, gy * 1024, 32, L);
  } else if (gy < 10){
    const int idx = gy - 2, mt = idx >> 1, ksp = idx & 1;
    gemm_body<true>(Awx, Wb + 4194304, Kp + ksp * KV_SLICE, nullptr,
                    512, mt * 128, nt * 128, ksp * 1024, 32, L);
  } else {
    const int idx = gy - 10, mt = idx >> 1, ksp = idx & 1;
    gemm_body<true>(Awx, Wb + 8388608, Vp + ksp * KV_SLICE, nullptr,
                    512, mt * 128, nt * 128, ksp * 1024, 32, L);
  }
}

// O-projection: splitK=2, grid (16 nt, 2 mt, 2 ksp) -> 2 f32 Yo slices, 32 steps.
__global__ __launch_bounds__(256, 2) void o_kernel(
    const unsigned short* __restrict__ Ao, const unsigned short* __restrict__ Wb,
    float* __restrict__ Yop)
{
  __shared__ __align__(16) unsigned short L[32768];
  gemm_body<false>(Ao, Wb + 12582912, nullptr, Yop + (size_t)blockIdx.z * YO_STRIDE,
                   132, blockIdx.y * 128, blockIdx.x * 128, blockIdx.z * 1024, 32, L);
}

// ---------------- attention: chunks 992..1023 only, per (b,h) block ----------------
// Sums the 2 bf16 split-K partial slices of Q/K/V during LDS staging.
__global__ __launch_bounds__(256) void attn_kernel(
    const unsigned short* __restrict__ Qp, const unsigned short* __restrict__ Kp,
    const unsigned short* __restrict__ Vp, const int* __restrict__ amask,
    unsigned short* __restrict__ Ao)
{
  const int b = blockIdx.x >> 4;
  const int h = blockIdx.x & 15;
  __shared__ float Qs[32][129];
  __shared__ unsigned int Ks[128][65];
  __shared__ unsigned int Vs[128][65];
  __shared__ float Wt[32][132];
  __shared__ float msk[128];
  const int tid = threadIdx.x;

  for (int i = tid; i < 32 * 128; i += 256){
    int cq = i >> 7, d = i & 127;
    size_t off = (size_t)(b * 32 + cq) * 2048 + h * 128 + d;
    Qs[cq][d] = bf2f(Qp[off]) + bf2f(Qp[off + QP_SLICE]);
  }
  for (int i = tid; i < 128 * 64; i += 256){
    int j = i >> 6, du = i & 63;
    size_t off = (size_t)(b * 128 + j) * 2048 + h * 128 + du * 2;
    unsigned int k0 = *(const unsigned int*)(Kp + off);
    unsigned int k1 = *(const unsigned int*)(Kp + off + KV_SLICE);
    unsigned int v0 = *(const unsigned int*)(Vp + off);
    unsigned int v1 = *(const unsigned int*)(Vp + off + KV_SLICE);
    Ks[j][du] = pk2(bflo(k0) + bflo(k1), bfhi(k0) + bfhi(k1));
    Vs[j][du] = pk2(bflo(v0) + bflo(v1), bfhi(v0) + bfhi(v1));
  }
  if (tid < 128){
    msk[tid] = (amask[b * 4096 + 3968 + tid] != 0) ? 1.f : 0.f;
    size_t off = (size_t)(b * 128) * 2048 + h * 128 + tid;
    Ao[(size_t)(b * 33) * 2048 + h * 128 + tid] =
        f2bf(bf2f(Vp[off]) + bf2f(Vp[off + KV_SLICE]));
  }
  __syncthreads();

  const int cq = tid >> 3, jg = tid & 7;
  const int jmax = 4 * cq + 3;   // causal: j <= 4*cq+3 for chunk 992+cq
  const float scale = 0.088388347648318447f; // 1/sqrt(128)

  float s[16];
  {
    float sacc[16];
    #pragma unroll
    for (int jj = 0; jj < 16; ++jj) sacc[jj] = 0.f;
    for (int du = 0; du < 64; ++du){
      float q0 = Qs[cq][2 * du], q1 = Qs[cq][2 * du + 1];
      #pragma unroll
      for (int jj = 0; jj < 16; ++jj){
        unsigned int u = Ks[jg * 16 + jj][du];
        sacc[jj] += q0 * bflo(u) + q1 * bfhi(u);
      }
    }
    #pragma unroll
    for (int jj = 0; jj < 16; ++jj){
      int j = jg * 16 + jj;
      bool ok = (j <= jmax) && (msk[j] > 0.5f);
      s[jj] = ok ? sacc[jj] * scale : -1e9f;
    }
  }
  float m = s[0];
  #pragma unroll
  for (int jj = 1; jj < 16; ++jj) m = fmaxf(m, s[jj]);
  #pragma unroll
  for (int off = 1; off < 8; off <<= 1) m = fmaxf(m, __shfl_xor(m, off, 8));
  float sum = 0.f;
  #pragma unroll
  for (int jj = 0; jj < 16; ++jj){ s[jj] = expf(s[jj] - m); sum += s[jj]; }
  #pragma unroll
  for (int off = 1; off < 8; off <<= 1) sum += __shfl_xor(sum, off, 8);
  const float inv = 1.f / sum;
  #pragma unroll
  for (int jj = 0; jj < 16; ++jj) Wt[cq][jg * 16 + jj] = s[jj] * inv;
  __syncthreads();

  const int dg = tid & 7;
  float o[16];
  #pragma unroll
  for (int e = 0; e < 16; ++e) o[e] = 0.f;
  for (int j = 0; j < 128; ++j){
    float w = Wt[cq][j];
    #pragma unroll
    for (int du = 0; du < 8; ++du){
      unsigned int u = Vs[j][dg * 8 + du];
      o[2 * du]     += w * bflo(u);
      o[2 * du + 1] += w * bfhi(u);
    }
  }
  unsigned short* dst = Ao + (size_t)(b * 33 + 1 + cq) * 2048 + h * 128 + dg * 16;
  #pragma unroll
  for (int e = 0; e < 16; ++e) dst[e] = f2bf(o[e]);
}

// -------- resize: sum 2 Yo slices, linear upsample Cs=1024 -> S=4096 --------
__global__ __launch_bounds__(256) void resize_kernel(
    const float* __restrict__ Yop, float* __restrict__ out)
{
  const int rowid = blockIdx.x;
  const int b = rowid >> 12;
  const int i = rowid & 4095;
  float c  = i * 0.25f - 0.375f;
  float fl = floorf(c);
  int   j0 = (int)fl;
  float f  = c - fl;
  int   j1 = j0 + 1;
  j0 = max(0, min(j0, 1023));
  j1 = max(0, min(j1, 1023));
  const int ri0 = b * 33 + (j0 <= 991 ? 0 : j0 - 991);
  const int ri1 = b * 33 + (j1 <= 991 ? 0 : j1 - 991);
  const float* r0 = Yop + (size_t)ri0 * 2048;
  const float* r1 = Yop + (size_t)ri1 * 2048;
  float* op = out + (size_t)rowid * 2048;
  const int t = threadIdx.x;
  const bool same = (ri0 == ri1);
  #pragma unroll
  for (int q = 0; q < 2; ++q){
    int d = q * 1024 + t * 4;
    float4 a0 = *(const float4*)(r0 + d);
    float4 a1 = *(const float4*)(r0 + d + YO_STRIDE);
    float4 a;
    a.x = a0.x + a1.x; a.y = a0.y + a1.y; a.z = a0.z + a1.z; a.w = a0.w + a1.w;
    float4 o = a;
    if (!same){
      float4 b0 = *(const float4*)(r1 + d);
      float4 b1 = *(const float4*)(r1 + d + YO_STRIDE);
      float4 bb;
      bb.x = b0.x + b1.x; bb.y = b0.y + b1.y; bb.z = b0.z + b1.z; bb.w = b0.w + b1.w;
      o.x = a.x + f * (bb.x - a.x);
      o.y = a.y + f * (bb.y - a.y);
      o.z = a.z + f * (bb.z - a.z);
      o.w = a.w + f * (bb.w - a.w);
    }
    *(float4*)(op + d) = o;
  }
}

extern "C" void kernel_launch(void* const* d_in, const int* in_sizes, int n_in,
                              void* d_out, int out_size, void* d_ws, size_t ws_size,
                              hipStream_t stream)
{
  const float* inp   = (const float*)d_in[0];
  const int*   amask = (const int*)d_in[1];
  const float* Wq = (const float*)d_in[2];
  const float* Wk = (const float*)d_in[3];
  const float* Wv = (const float*)d_in[4];
  const float* Wo = (const float*)d_in[5];
  float* out = (float*)d_out;

  char* ws = (char*)d_ws;
  unsigned short* Wb  = (unsigned short*)(ws);             // 4 x 2048x2048 bf16 (33.5 MB)
  unsigned short* Aq  = (unsigned short*)(ws + 33554432);  // 128 x 2048 bf16
  unsigned short* Awx = (unsigned short*)(ws + 34078720);  // 512 x 2048 bf16
  unsigned short* Qp  = (unsigned short*)(ws + 36175872);  // 2 x [128x2048] bf16 partials
  unsigned short* Kp  = (unsigned short*)(ws + 37224448);  // 2 x [512x2048] bf16 partials
  unsigned short* Vp  = (unsigned short*)(ws + 41418752);  // 2 x [512x2048] bf16 partials
  unsigned short* Ao  = (unsigned short*)(ws + 45613056);  // 132 x 2048 bf16 (1 MB region, o stages to row 255)
  float*          Yop = (float*)(ws + 46661632);           // 2 x [132x2048] f32 partials

  prep_kernel<<<8832, 256, 0, stream>>>(inp, Wq, Wk, Wv, Wo, Wb, Awx, Aq);
  qkv_kernel<<<dim3(16, 18), 256, 0, stream>>>(Aq, Awx, Wb, Qp, Kp, Vp);
  attn_kernel<<<64, 256, 0, stream>>>(Qp, Kp, Vp, amask, Ao);
  o_kernel<<<dim3(16, 2, 2), 256, 0, stream>>>(Ao, Wb, Yop);
  resize_kernel<<<16384, 256, 0, stream>>>(Yop, out);
}

// Round 17
// 111.320 us; speedup vs baseline: 1.3495x; 1.0430x over previous
//
#include <hip/hip_runtime.h>
#include <hip/hip_bf16.h>

// B=4, S=4096, D=2048, H=16, dh=128, R=4, WIN=128, Cs=1024, ws=3968.
// Chunks 992..1023 live; chunks <=991 collapse to v[:,0,:].
//
// CHAMPION (round 12, 111.3 us): 5 dispatches:
//   prep_kernel  : weights f32->bf16 (Wb), window -> bf16 (Awx), means -> bf16 (Aq)
//   qkv_kernel   : 128x128/BK64 GEMM, global_load_lds + XOR swizzle, splitK=2
//                  -> bf16 partial slices (288 blocks, 16 steps each)
//   attn_kernel  : sums 2 partial slices during staging, 32x128 masked softmax
//   o_kernel     : same GEMM body, splitK=4 -> 4 f32 Yo slices (128 blocks, 8 steps)
//   resize_kernel: sums 4 Yo slices, clamped lerp upsample -> d_out

typedef __attribute__((ext_vector_type(8))) short short8;
typedef __attribute__((ext_vector_type(4))) float f32x4;

#define QP_SLICE  (128 * 2048)    // shorts per Q partial slice
#define KV_SLICE  (512 * 2048)    // shorts per K/V partial slice
#define YO_STRIDE (132 * 2048)    // floats per Yo partial slice

__device__ __forceinline__ unsigned short f2bf(float f){
  unsigned int x = __float_as_uint(f);
  return (unsigned short)((x + 0x7fffu + ((x >> 16) & 1u)) >> 16);
}
__device__ __forceinline__ float bf2f(unsigned short u){
  return __uint_as_float(((unsigned int)u) << 16);
}
__device__ __forceinline__ float bflo(unsigned int u){ return __uint_as_float(u << 16); }
__device__ __forceinline__ float bfhi(unsigned int u){ return __uint_as_float(u & 0xffff0000u); }
__device__ __forceinline__ unsigned int pk2(float lo, float hi){
  return ((unsigned int)f2bf(hi) << 16) | (unsigned int)f2bf(lo);
}
__device__ __forceinline__ short8 cvt8(float4 x, float4 y){
  union { unsigned int u[4]; short8 s; } r;
  r.u[0] = pk2(x.x, x.y); r.u[1] = pk2(x.z, x.w);
  r.u[2] = pk2(y.x, y.y); r.u[3] = pk2(y.z, y.w);
  return r.s;
}

// ---------- prep: weights + window + chunk-means -> bf16 ----------
__global__ __launch_bounds__(256) void prep_kernel(
    const float* __restrict__ inp,
    const float* __restrict__ Wq, const float* __restrict__ Wk,
    const float* __restrict__ Wv, const float* __restrict__ Wo,
    unsigned short* __restrict__ Wb,
    unsigned short* __restrict__ Awx, unsigned short* __restrict__ Aq)
{
  const int bx = blockIdx.x;
  if (bx < 8192){
    const int idx = bx * 256 + threadIdx.x;
    const int w = idx >> 19;
    const int sub = idx & 524287;
    const float* src = (w == 0) ? Wq : (w == 1) ? Wk : (w == 2) ? Wv : Wo;
    const float* p = src + (size_t)sub * 8;
    *(short8*)&Wb[(size_t)w * 4194304 + (size_t)sub * 8] =
        cvt8(*(const float4*)p, *(const float4*)(p + 4));
  } else if (bx < 8704){
    const int idx = (bx - 8192) * 256 + threadIdx.x;
    const int b = idx >> 15;
    const int j = (idx >> 8) & 127;
    const int d8 = (idx & 255) * 8;
    const float* p = inp + ((size_t)b * 4096 + 3968 + j) * 2048 + d8;
    *(short8*)&Awx[((size_t)b * 128 + j) * 2048 + d8] =
        cvt8(*(const float4*)p, *(const float4*)(p + 4));
  } else {
    const int idx = (bx - 8704) * 256 + threadIdx.x;
    const int b = idx >> 13;
    const int c = (idx >> 8) & 31;
    const int d8 = (idx & 255) * 8;
    const float* p = inp + ((size_t)b * 4096 + 3968 + 4 * c) * 2048 + d8;
    float4 x0 = *(const float4*)(p);
    float4 x1 = *(const float4*)(p + 2048);
    float4 x2 = *(const float4*)(p + 4096);
    float4 x3 = *(const float4*)(p + 6144);
    float4 y0 = *(const float4*)(p + 4);
    float4 y1 = *(const float4*)(p + 2052);
    float4 y2 = *(const float4*)(p + 4100);
    float4 y3 = *(const float4*)(p + 6148);
    float4 xm, ym;
    xm.x = 0.25f * (x0.x + x1.x + x2.x + x3.x);
    xm.y = 0.25f * (x0.y + x1.y + x2.y + x3.y);
    xm.z = 0.25f * (x0.z + x1.z + x2.z + x3.z);
    xm.w = 0.25f * (x0.w + x1.w + x2.w + x3.w);
    ym.x = 0.25f * (y0.x + y1.x + y2.x + y3.x);
    ym.y = 0.25f * (y0.y + y1.y + y2.y + y3.y);
    ym.z = 0.25f * (y0.z + y1.z + y2.z + y3.z);
    ym.w = 0.25f * (y0.w + y1.w + y2.w + y3.w);
    *(short8*)&Aq[((size_t)b * 32 + c) * 2048 + d8] = cvt8(xm, ym);
  }
}

// ---- stage one 128x64 A-tile + 128x64 B-tile into LDS via global_load_lds.
// Linear LDS dest; global source column pre-swizzled (unit ^ (row&7)); reads
// apply the same XOR -> conflict-free (rule 21).
__device__ __forceinline__ void stage_tile(
    const unsigned short* __restrict__ A, const unsigned short* __restrict__ W,
    int row0, int n0, int kt,
    unsigned short* As, unsigned short* Bs, int wid, int lane)
{
  const int r  = lane >> 3;
  const int ug = ((lane & 7) ^ r) * 8;
  #pragma unroll
  for (int i = 0; i < 4; ++i){
    const int c = wid * 4 + i;
    __builtin_amdgcn_global_load_lds(
        (const __attribute__((address_space(1))) void*)(A + (size_t)(row0 + c * 8 + r) * 2048 + kt + ug),
        (__attribute__((address_space(3))) void*)(As + c * 512),
        16, 0, 0);
    __builtin_amdgcn_global_load_lds(
        (const __attribute__((address_space(1))) void*)(W + (size_t)(n0 + c * 8 + r) * 2048 + kt + ug),
        (__attribute__((address_space(3))) void*)(Bs + c * 512),
        16, 0, 0);
  }
}

// ---- GEMM slice: C[row0..+127, n0..+127] = A[.,kbase..+64*nsteps) @ W^T,
// 4 waves (2x2 of 64x64), 16x16x32 bf16 MFMA, gload_lds + double-buffered LDS.
template<bool OUT_BF16>
__device__ __forceinline__ void gemm_body(
    const unsigned short* __restrict__ A, const unsigned short* __restrict__ W,
    unsigned short* __restrict__ Cb, float* __restrict__ Cf,
    int M, int row0, int n0, int kbase, int nsteps,
    unsigned short* L)
{
  const int tid  = threadIdx.x;
  const int lane = tid & 63;
  const int wid  = tid >> 6;
  const int wr = wid >> 1, wc = wid & 1;

  f32x4 acc[4][4] = {};

  stage_tile(A, W, row0, n0, kbase, L, L + 8192, wid, lane);
  int cur = 0;

  for (int t = 0; t < nsteps; ++t){
    __syncthreads();
    const int nxt = cur ^ 1;
    if (t + 1 < nsteps)
      stage_tile(A, W, row0, n0, kbase + (t + 1) * 64,
                 L + nxt * 16384, L + nxt * 16384 + 8192, wid, lane);
    const unsigned short* As = L + cur * 16384;
    const unsigned short* Bs = As + 8192;
    #pragma unroll
    for (int ks = 0; ks < 2; ++ks){
      short8 av[4], bv[4];
      const int unit = ks * 4 + (lane >> 4);
      #pragma unroll
      for (int f = 0; f < 4; ++f){
        const int row = wr * 64 + f * 16 + (lane & 15);
        av[f] = *(const short8*)&As[row * 64 + ((unit ^ (row & 7)) * 8)];
      }
      #pragma unroll
      for (int n = 0; n < 4; ++n){
        const int row = wc * 64 + n * 16 + (lane & 15);
        bv[n] = *(const short8*)&Bs[row * 64 + ((unit ^ (row & 7)) * 8)];
      }
      #pragma unroll
      for (int f = 0; f < 4; ++f)
        #pragma unroll
        for (int n = 0; n < 4; ++n)
          acc[f][n] = __builtin_amdgcn_mfma_f32_16x16x32_bf16(av[f], bv[n], acc[f][n], 0, 0, 0);
    }
    cur = nxt;
  }

  #pragma unroll
  for (int f = 0; f < 4; ++f){
    #pragma unroll
    for (int n = 0; n < 4; ++n){
      const int col = n0 + wc * 64 + n * 16 + (lane & 15);
      #pragma unroll
      for (int r = 0; r < 4; ++r){
        const int row = row0 + wr * 64 + f * 16 + (lane >> 4) * 4 + r;
        if (row < M){
          if (OUT_BF16) Cb[(size_t)row * 2048 + col] = f2bf(acc[f][n][r]);
          else          Cf[(size_t)row * 2048 + col] = acc[f][n][r];
        }
      }
    }
  }
}

// grid (16 nt, 18 gy): gy<2 -> Q (ksp=gy); gy in [2,10) -> K; [10,18) -> V
// (idx = gy-base: mt = idx>>1, ksp = idx&1). splitK=2, K-slice=1024, 16 steps.
__global__ __launch_bounds__(256, 2) void qkv_kernel(
    const unsigned short* __restrict__ Aq, const unsigned short* __restrict__ Awx,
    const unsigned short* __restrict__ Wb,
    unsigned short* __restrict__ Qp, unsigned short* __restrict__ Kp,
    unsigned short* __restrict__ Vp)
{
  __shared__ __align__(16) unsigned short L[32768];   // 64 KB
  const int nt = blockIdx.x, gy = blockIdx.y;
  if (gy < 2){
    gemm_body<true>(Aq, Wb, Qp + gy * QP_SLICE, nullptr,
                    128, 0, nt * 128, gy * 1024, 16, L);
  } else if (gy < 10){
    const int idx = gy - 2, mt = idx >> 1, ksp = idx & 1;
    gemm_body<true>(Awx, Wb + 4194304, Kp + ksp * KV_SLICE, nullptr,
                    512, mt * 128, nt * 128, ksp * 1024, 16, L);
  } else {
    const int idx = gy - 10, mt = idx >> 1, ksp = idx & 1;
    gemm_body<true>(Awx, Wb + 8388608, Vp + ksp * KV_SLICE, nullptr,
                    512, mt * 128, nt * 128, ksp * 1024, 16, L);
  }
}

// O-projection: splitK=4, grid (16 nt, 2 mt, 4 ksp) -> 4 f32 Yo slices, 8 steps.
__global__ __launch_bounds__(256, 2) void o_kernel(
    const unsigned short* __restrict__ Ao, const unsigned short* __restrict__ Wb,
    float* __restrict__ Yop)
{
  __shared__ __align__(16) unsigned short L[32768];
  gemm_body<false>(Ao, Wb + 12582912, nullptr, Yop + (size_t)blockIdx.z * YO_STRIDE,
                   132, blockIdx.y * 128, blockIdx.x * 128, blockIdx.z * 512, 8, L);
}

// ---------------- attention: chunks 992..1023 only, per (b,h) block ----------------
// Sums the 2 bf16 split-K partial slices of Q/K/V during LDS staging.
__global__ __launch_bounds__(256) void attn_kernel(
    const unsigned short* __restrict__ Qp, const unsigned short* __restrict__ Kp,
    const unsigned short* __restrict__ Vp, const int* __restrict__ amask,
    unsigned short* __restrict__ Ao)
{
  const int b = blockIdx.x >> 4;
  const int h = blockIdx.x & 15;
  __shared__ float Qs[32][129];
  __shared__ unsigned int Ks[128][65];
  __shared__ unsigned int Vs[128][65];
  __shared__ float Wt[32][132];
  __shared__ float msk[128];
  const int tid = threadIdx.x;

  for (int i = tid; i < 32 * 128; i += 256){
    int cq = i >> 7, d = i & 127;
    size_t off = (size_t)(b * 32 + cq) * 2048 + h * 128 + d;
    Qs[cq][d] = bf2f(Qp[off]) + bf2f(Qp[off + QP_SLICE]);
  }
  for (int i = tid; i < 128 * 64; i += 256){
    int j = i >> 6, du = i & 63;
    size_t off = (size_t)(b * 128 + j) * 2048 + h * 128 + du * 2;
    unsigned int k0 = *(const unsigned int*)(Kp + off);
    unsigned int k1 = *(const unsigned int*)(Kp + off + KV_SLICE);
    unsigned int v0 = *(const unsigned int*)(Vp + off);
    unsigned int v1 = *(const unsigned int*)(Vp + off + KV_SLICE);
    Ks[j][du] = pk2(bflo(k0) + bflo(k1), bfhi(k0) + bfhi(k1));
    Vs[j][du] = pk2(bflo(v0) + bflo(v1), bfhi(v0) + bfhi(v1));
  }
  if (tid < 128){
    msk[tid] = (amask[b * 4096 + 3968 + tid] != 0) ? 1.f : 0.f;
    size_t off = (size_t)(b * 128) * 2048 + h * 128 + tid;
    Ao[(size_t)(b * 33) * 2048 + h * 128 + tid] =
        f2bf(bf2f(Vp[off]) + bf2f(Vp[off + KV_SLICE]));
  }
  __syncthreads();

  const int cq = tid >> 3, jg = tid & 7;
  const int jmax = 4 * cq + 3;   // causal: j <= 4*cq+3 for chunk 992+cq
  const float scale = 0.088388347648318447f; // 1/sqrt(128)

  float s[16];
  {
    float sacc[16];
    #pragma unroll
    for (int jj = 0; jj < 16; ++jj) sacc[jj] = 0.f;
    for (int du = 0; du < 64; ++du){
      float q0 = Qs[cq][2 * du], q1 = Qs[cq][2 * du + 1];
      #pragma unroll
      for (int jj = 0; jj < 16; ++jj){
        unsigned int u = Ks[jg * 16 + jj][du];
        sacc[jj] += q0 * bflo(u) + q1 * bfhi(u);
      }
    }
    #pragma unroll
    for (int jj = 0; jj < 16; ++jj){
      int j = jg * 16 + jj;
      bool ok = (j <= jmax) && (msk[j] > 0.5f);
      s[jj] = ok ? sacc[jj] * scale : -1e9f;
    }
  }
  float m = s[0];
  #pragma unroll
  for (int jj = 1; jj < 16; ++jj) m = fmaxf(m, s[jj]);
  #pragma unroll
  for (int off = 1; off < 8; off <<= 1) m = fmaxf(m, __shfl_xor(m, off, 8));
  float sum = 0.f;
  #pragma unroll
  for (int jj = 0; jj < 16; ++jj){ s[jj] = expf(s[jj] - m); sum += s[jj]; }
  #pragma unroll
  for (int off = 1; off < 8; off <<= 1) sum += __shfl_xor(sum, off, 8);
  const float inv = 1.f / sum;
  #pragma unroll
  for (int jj = 0; jj < 16; ++jj) Wt[cq][jg * 16 + jj] = s[jj] * inv;
  __syncthreads();

  const int dg = tid & 7;
  float o[16];
  #pragma unroll
  for (int e = 0; e < 16; ++e) o[e] = 0.f;
  for (int j = 0; j < 128; ++j){
    float w = Wt[cq][j];
    #pragma unroll
    for (int du = 0; du < 8; ++du){
      unsigned int u = Vs[j][dg * 8 + du];
      o[2 * du]     += w * bflo(u);
      o[2 * du + 1] += w * bfhi(u);
    }
  }
  unsigned short* dst = Ao + (size_t)(b * 33 + 1 + cq) * 2048 + h * 128 + dg * 16;
  #pragma unroll
  for (int e = 0; e < 16; ++e) dst[e] = f2bf(o[e]);
}

// -------- resize: sum 4 Yo slices, linear upsample Cs=1024 -> S=4096 --------
__global__ __launch_bounds__(256) void resize_kernel(
    const float* __restrict__ Yop, float* __restrict__ out)
{
  const int rowid = blockIdx.x;
  const int b = rowid >> 12;
  const int i = rowid & 4095;
  float c  = i * 0.25f - 0.375f;
  float fl = floorf(c);
  int   j0 = (int)fl;
  float f  = c - fl;
  int   j1 = j0 + 1;
  j0 = max(0, min(j0, 1023));
  j1 = max(0, min(j1, 1023));
  const int ri0 = b * 33 + (j0 <= 991 ? 0 : j0 - 991);
  const int ri1 = b * 33 + (j1 <= 991 ? 0 : j1 - 991);
  const float* r0 = Yop + (size_t)ri0 * 2048;
  const float* r1 = Yop + (size_t)ri1 * 2048;
  float* op = out + (size_t)rowid * 2048;
  const int t = threadIdx.x;
  const bool same = (ri0 == ri1);
  #pragma unroll
  for (int q = 0; q < 2; ++q){
    int d = q * 1024 + t * 4;
    float4 a0 = *(const float4*)(r0 + d);
    float4 a1 = *(const float4*)(r0 + d + YO_STRIDE);
    float4 a2 = *(const float4*)(r0 + d + 2 * YO_STRIDE);
    float4 a3 = *(const float4*)(r0 + d + 3 * YO_STRIDE);
    float4 a;
    a.x = a0.x + a1.x + a2.x + a3.x;
    a.y = a0.y + a1.y + a2.y + a3.y;
    a.z = a0.z + a1.z + a2.z + a3.z;
    a.w = a0.w + a1.w + a2.w + a3.w;
    float4 o = a;
    if (!same){
      float4 b0 = *(const float4*)(r1 + d);
      float4 b1 = *(const float4*)(r1 + d + YO_STRIDE);
      float4 b2 = *(const float4*)(r1 + d + 2 * YO_STRIDE);
      float4 b3 = *(const float4*)(r1 + d + 3 * YO_STRIDE);
      float4 bb;
      bb.x = b0.x + b1.x + b2.x + b3.x;
      bb.y = b0.y + b1.y + b2.y + b3.y;
      bb.z = b0.z + b1.z + b2.z + b3.z;
      bb.w = b0.w + b1.w + b2.w + b3.w;
      o.x = a.x + f * (bb.x - a.x);
      o.y = a.y + f * (bb.y - a.y);
      o.z = a.z + f * (bb.z - a.z);
      o.w = a.w + f * (bb.w - a.w);
    }
    *(float4*)(op + d) = o;
  }
}

extern "C" void kernel_launch(void* const* d_in, const int* in_sizes, int n_in,
                              void* d_out, int out_size, void* d_ws, size_t ws_size,
                              hipStream_t stream)
{
  const float* inp   = (const float*)d_in[0];
  const int*   amask = (const int*)d_in[1];
  const float* Wq = (const float*)d_in[2];
  const float* Wk = (const float*)d_in[3];
  const float* Wv = (const float*)d_in[4];
  const float* Wo = (const float*)d_in[5];
  float* out = (float*)d_out;

  char* ws = (char*)d_ws;
  unsigned short* Wb  = (unsigned short*)(ws);             // 4 x 2048x2048 bf16 (33.5 MB)
  unsigned short* Aq  = (unsigned short*)(ws + 33554432);  // 128 x 2048 bf16
  unsigned short* Awx = (unsigned short*)(ws + 34078720);  // 512 x 2048 bf16
  unsigned short* Qp  = (unsigned short*)(ws + 36175872);  // 2 x [128x2048] bf16 partials
  unsigned short* Kp  = (unsigned short*)(ws + 37224448);  // 2 x [512x2048] bf16 partials
  unsigned short* Vp  = (unsigned short*)(ws + 41418752);  // 2 x [512x2048] bf16 partials
  unsigned short* Ao  = (unsigned short*)(ws + 45613056);  // 132 x 2048 bf16 (1 MB region, o stages to row 255)
  float*          Yop = (float*)(ws + 46661632);           // 4 x [132x2048] f32 partials

  prep_kernel<<<8832, 256, 0, stream>>>(inp, Wq, Wk, Wv, Wo, Wb, Awx, Aq);
  qkv_kernel<<<dim3(16, 18), 256, 0, stream>>>(Aq, Awx, Wb, Qp, Kp, Vp);
  attn_kernel<<<64, 256, 0, stream>>>(Qp, Kp, Vp, amask, Ao);
  o_kernel<<<dim3(16, 2, 4), 256, 0, stream>>>(Ao, Wb, Yop);
  resize_kernel<<<16384, 256, 0, stream>>>(Yop, out);
}